// Round 1
// baseline (158.268 us; speedup 1.0000x reference)
//
#include <hip/hip_runtime.h>

// KANN_4578435137547: quadratic Lagrange FEM basis + weight contraction.
// N_WIDTH=8, N_ORDER=2, N_ELEMENTS=1024, N_NODES=2049, N_SAMPLES=4096.
// Outputs (flat, f32, concat): t[4096,8], dt[4096,8], ddt[4096,8],
//   phi[4096,8,2049], dphi[...], ddphi[...]  (total 201,621,504 floats).
// phi arrays are zero except 3 entries/row -> memset whole d_out, scatter.

#define KN_WIDTH    8
#define KN_ORDER    2
#define KN_ELEMENTS 1024
#define KN_NODES    2049
#define KN_SAMPLES  4096

__global__ __launch_bounds__(256)
void KANN_4578435137547_scatter(const float* __restrict__ x,
                                const float* __restrict__ w,
                                float* __restrict__ out) {
    int i = blockIdx.x * blockDim.x + threadIdx.x;
    if (i >= KN_SAMPLES) return;

    float xv = x[i];
    // x_shift = (N_NODES-1) * (x - 0) / (1 - 0)
    float x_shift = 2048.0f * xv;
    float fid = floorf(x_shift * 0.5f);
    fid = fminf(fmaxf(fid, 0.0f), (float)(KN_ELEMENTS - 1));
    int nodes_l = (int)fid * KN_ORDER;                 // even, in [0, 2046]
    float x_t = x_shift - ((float)nodes_l + 1.0f);     // /(0.5*order)=1

    // Quadratic Lagrange at ref nodes {-1,0,1}
    float phi0 = 0.5f * x_t * (x_t - 1.0f);
    float phi1 = 1.0f - x_t * x_t;
    float phi2 = 0.5f * x_t * (x_t + 1.0f);

    const float inv_dx  = 2048.0f;            // 1/delta_x, delta_x = 1/2048
    const float inv_dx2 = inv_dx * inv_dx;
    float dphi0 = (x_t - 0.5f) * inv_dx;
    float dphi1 = (-2.0f * x_t) * inv_dx;
    float dphi2 = (x_t + 0.5f) * inv_dx;
    float dd0 =  1.0f * inv_dx2;
    float dd1 = -2.0f * inv_dx2;
    float dd2 =  1.0f * inv_dx2;

    const long long off_dt  = (long long)KN_SAMPLES * KN_WIDTH;       // 32768
    const long long off_phi = 3LL * KN_SAMPLES * KN_WIDTH;            // 98304
    const long long sz_phi  = (long long)KN_SAMPLES * KN_WIDTH * KN_NODES;

#pragma unroll
    for (int k = 0; k < KN_WIDTH; ++k) {
        const float* wk = w + k * KN_NODES + nodes_l;
        float w0 = wk[0], w1 = wk[1], w2 = wk[2];
        float t   = w0 * phi0  + w1 * phi1  + w2 * phi2;
        float dt  = w0 * dphi0 + w1 * dphi1 + w2 * dphi2;
        float ddt = w0 * dd0   + w1 * dd1   + w2 * dd2;

        long long ik = (long long)i * KN_WIDTH + k;
        out[ik]              = t;
        out[off_dt + ik]     = dt;
        out[2 * off_dt + ik] = ddt;

        long long base = off_phi + ik * KN_NODES + nodes_l;
        out[base + 0] = phi0;
        out[base + 1] = phi1;
        out[base + 2] = phi2;
        out[base + sz_phi + 0] = dphi0;
        out[base + sz_phi + 1] = dphi1;
        out[base + sz_phi + 2] = dphi2;
        out[base + 2 * sz_phi + 0] = dd0;
        out[base + 2 * sz_phi + 1] = dd1;
        out[base + 2 * sz_phi + 2] = dd2;
    }
}

extern "C" void kernel_launch(void* const* d_in, const int* in_sizes, int n_in,
                              void* d_out, int out_size, void* d_ws, size_t ws_size,
                              hipStream_t stream) {
    const float* x = (const float*)d_in[0];
    const float* w = (const float*)d_in[1];
    float* out = (float*)d_out;

    // Zero the whole output (phi arrays are ~all zeros); graph-capturable.
    hipMemsetAsync(out, 0, (size_t)out_size * sizeof(float), stream);

    const int block = 256;
    const int grid = (KN_SAMPLES + block - 1) / block;   // 16 blocks
    KANN_4578435137547_scatter<<<grid, block, 0, stream>>>(x, w, out);
}